// Round 21
// baseline (124.231 us; speedup 1.0000x reference)
//
#include <hip/hip_runtime.h>

namespace {
constexpr int kB  = 2;
constexpr int kL  = 2048;
constexpr int kD  = 1024;
constexpr int kH  = 16;
constexpr int kHD = 64;
constexpr int kM  = kB * kL;      // 4096 total rows
}

typedef _Float16 f16x8 __attribute__((ext_vector_type(8)));
typedef float    f32x16 __attribute__((ext_vector_type(16)));
typedef unsigned int u32;

union Frag16 { uint4 u4; unsigned u[4]; f16x8 v; };

__device__ __forceinline__ unsigned short f2h(float f) {
    return __builtin_bit_cast(unsigned short, (_Float16)f);
}
__device__ __forceinline__ unsigned pk2(float a, float b) {
    return __builtin_bit_cast(unsigned, __builtin_amdgcn_cvt_pkrtz(a, b));
}

// async 16B global -> LDS (wave-uniform LDS base; HW adds lane*16)
__device__ __forceinline__ void gload16(const void* g, void* l) {
    __builtin_amdgcn_global_load_lds(
        (const __attribute__((address_space(1))) u32*)g,
        (__attribute__((address_space(3))) u32*)(unsigned long long)(__builtin_bit_cast(unsigned long long, l)),
        16, 0, 0);
}

// ---------------------------------------------------------------------------
// Fused prep: blocks 0..6143 cast q,k,v fp32->fp16; blocks 6144..7167
// transpose-cast the 4 weight matrices to [n][k] fp16. One launch, grid 7168.
// ---------------------------------------------------------------------------
__global__ __launch_bounds__(256) void prep_kernel(
    const float* __restrict__ q, const float* __restrict__ k,
    const float* __restrict__ v, unsigned short* __restrict__ dstA,
    const float* __restrict__ W0, const float* __restrict__ W1,
    const float* __restrict__ W2, const float* __restrict__ W3,
    unsigned short* __restrict__ WtBase)
{
    __shared__ _Float16 T[64][68];
    const int id = blockIdx.x;
    if (id < 6144) {
        const int yy = id >> 11;            // 0..2 (src select)
        const int xx = id & 2047;
        const float* src = yy == 0 ? q : (yy == 1 ? k : v);
        unsigned short* d = dstA + (size_t)yy * ((size_t)kM * kD);
        const size_t i = ((size_t)xx * 256 + threadIdx.x) * 8;
        const float4 f0 = *(const float4*)(src + i);
        const float4 f1 = *(const float4*)(src + i + 4);
        _Float16 h[8];
        h[0] = (_Float16)f0.x; h[1] = (_Float16)f0.y;
        h[2] = (_Float16)f0.z; h[3] = (_Float16)f0.w;
        h[4] = (_Float16)f1.x; h[5] = (_Float16)f1.y;
        h[6] = (_Float16)f1.z; h[7] = (_Float16)f1.w;
        *(uint4*)(d + i) = *(uint4*)h;
        return;
    }
    const int id2 = id - 6144;              // 0..1023
    const int z = id2 >> 8;                 // weight select
    const int rem = id2 & 255;
    const int by = rem >> 4, bx = rem & 15;
    const float* W = z == 0 ? W0 : z == 1 ? W1 : z == 2 ? W2 : W3;
    unsigned short* Wt = WtBase + (size_t)z * ((size_t)kD * kD);
    const int k0 = by * 64, n0 = bx * 64;
    const int tx = threadIdx.x & 15, ty = threadIdx.x >> 4;
#pragma unroll
    for (int i = 0; i < 4; ++i) {
        const int kk = i * 16 + ty;
        const float4 w = *(const float4*)&W[(size_t)(k0 + kk) * kD + n0 + tx * 4];
        T[tx * 4 + 0][kk] = (_Float16)w.x;
        T[tx * 4 + 1][kk] = (_Float16)w.y;
        T[tx * 4 + 2][kk] = (_Float16)w.z;
        T[tx * 4 + 3][kk] = (_Float16)w.w;
    }
    __syncthreads();
#pragma unroll
    for (int i = 0; i < 4; ++i) {
        const int nn = i * 16 + ty;
        *(ushort4*)&Wt[(size_t)(n0 + nn) * kD + k0 + tx * 4] = *(ushort4*)&T[nn][tx * 4];
    }
}

// ---------------------------------------------------------------------------
// Fused QKV fp16 GEMM, 128x128/BK=64/2-buffer, grid 768 (2 blocks/CU).
// proj=bxp>>3; A at A+proj*MD, W at Wt+proj*DD.
// Q -> heads, PRE-SCALED by 0.125*log2(e). K -> heads. V -> transposed heads
// (B,H,HD,L) with keys QUAD-PERMUTED (l ^= 12 on middle quads) so attention's
// P-fragments need no cross-lane exchange.
// ---------------------------------------------------------------------------
__global__ __launch_bounds__(256) void gemm_qkv_kernel(
    const unsigned short* __restrict__ A, const unsigned short* __restrict__ Wt,
    const float* __restrict__ bq, const float* __restrict__ bk,
    const float* __restrict__ bv, unsigned short* __restrict__ Qh,
    unsigned short* __restrict__ Kh, unsigned short* __restrict__ Vt)
{
    __shared__ unsigned short Als[2][128 * 64];
    __shared__ unsigned short Bls[2][128 * 64];

    const int tid = threadIdx.x;
    const int lane = tid & 63;
    const int wid = tid >> 6;
    const int l31 = lane & 31;
    const int hi = lane >> 5;
    const int by = blockIdx.x & 31;
    const int bxp = blockIdx.x >> 5;        // 0..23
    const int proj = bxp >> 3;              // 0=q 1=k 2=v
    const int bx = bxp & 7;                 // col tile within proj
    const int row0 = by * 128;
    const int col0 = bx * 128;
    const int wr = wid >> 1, wc = wid & 1;

    const int rl = lane >> 3;
    const int sl = lane & 7;
    const int ssrc = (sl ^ rl) * 8;

    const unsigned short* Aproj = A + (size_t)proj * ((size_t)kM * kD);
    const unsigned short* Wproj = Wt + (size_t)proj * ((size_t)kD * kD);
    const unsigned short* Abase = Aproj + (size_t)(row0 + wid * 32 + rl) * kD + ssrc;
    const unsigned short* Bbase = Wproj + (size_t)(col0 + wid * 32 + rl) * kD + ssrc;

    f32x16 acc00{}, acc01{}, acc10{}, acc11{};

    auto stage = [&](int kt, int buf) {
#pragma unroll
        for (int i = 0; i < 4; ++i) {
            gload16(Abase + (size_t)(i * 8) * kD + kt * 64,
                    &Als[buf][(wid * 32 + i * 8) * 64]);
        }
#pragma unroll
        for (int i = 0; i < 4; ++i) {
            gload16(Bbase + (size_t)(i * 8) * kD + kt * 64,
                    &Bls[buf][(wid * 32 + i * 8) * 64]);
        }
    };

    const int ra0 = wr * 64 + l31;
    const int cb0 = wc * 64 + l31;

    stage(0, 0);
    int cur = 0;
    for (int kt = 0; kt < kD / 64; ++kt) {
        __syncthreads();
        if (kt + 1 < kD / 64) stage(kt + 1, cur ^ 1);
#pragma unroll
        for (int ks = 0; ks < 4; ++ks) {
            const int slot = (ks << 1) | hi;
            Frag16 a0, a1, b0, b1;
            a0.u4 = *(const uint4*)&Als[cur][ra0 * 64 + ((slot ^ (ra0 & 7)) << 3)];
            a1.u4 = *(const uint4*)&Als[cur][(ra0 + 32) * 64 + ((slot ^ ((ra0 + 32) & 7)) << 3)];
            b0.u4 = *(const uint4*)&Bls[cur][cb0 * 64 + ((slot ^ (cb0 & 7)) << 3)];
            b1.u4 = *(const uint4*)&Bls[cur][(cb0 + 32) * 64 + ((slot ^ ((cb0 + 32) & 7)) << 3)];
            acc00 = __builtin_amdgcn_mfma_f32_32x32x16_f16(a0.v, b0.v, acc00, 0, 0, 0);
            acc01 = __builtin_amdgcn_mfma_f32_32x32x16_f16(a0.v, b1.v, acc01, 0, 0, 0);
            acc10 = __builtin_amdgcn_mfma_f32_32x32x16_f16(a1.v, b0.v, acc10, 0, 0, 0);
            acc11 = __builtin_amdgcn_mfma_f32_32x32x16_f16(a1.v, b1.v, acc11, 0, 0, 0);
        }
        cur ^= 1;
    }

    // ---- epilogue ----
    const float* bias = proj == 0 ? bq : (proj == 1 ? bk : bv);
    const float bias0 = bias[col0 + wc * 64 + l31];
    const float bias1 = bias[col0 + wc * 64 + 32 + l31];
    const float oscale = proj == 0 ? (0.125f * 1.44269504089f) : 1.0f;

    const f32x16* accs[2][2] = {{&acc00, &acc01}, {&acc10, &acc11}};
#pragma unroll
    for (int rt = 0; rt < 2; ++rt) {
#pragma unroll
        for (int ct = 0; ct < 2; ++ct) {
            const f32x16& acv = *accs[rt][ct];
            const float bb = ct ? bias1 : bias0;
            const int c = col0 + wc * 64 + ct * 32 + l31;
            if (proj == 2) {
                // V transposed heads: [b][h][hd][l], l quad-permuted (1<->2 per 16)
#pragma unroll
                for (int qd = 0; qd < 4; ++qd) {
                    const int r = row0 + wr * 64 + rt * 32 + 8 * qd + 4 * hi;
                    const int b_ = r >> 11;
                    int l_ = r & (kL - 1);
                    l_ ^= ((((l_ >> 2) ^ (l_ >> 3)) & 1) ? 12 : 0);
                    ushort4 w;
                    w.x = f2h(acv[4 * qd + 0] + bb);
                    w.y = f2h(acv[4 * qd + 1] + bb);
                    w.z = f2h(acv[4 * qd + 2] + bb);
                    w.w = f2h(acv[4 * qd + 3] + bb);
                    *(ushort4*)&Vt[((size_t)(b_ * kH + (c >> 6)) * kHD + (c & 63)) * kL + l_] = w;
                }
            } else {
                unsigned short* C = proj == 0 ? Qh : Kh;
#pragma unroll
                for (int reg = 0; reg < 16; ++reg) {
                    const int r = row0 + wr * 64 + rt * 32 + (reg & 3) + 8 * (reg >> 2) + 4 * hi;
                    const int b_ = r >> 11, l_ = r & (kL - 1);
                    C[((size_t)(b_ * kH + (c >> 6)) * kL + l_) * kHD + (c & 63)] =
                        f2h((acv[reg] + bb) * oscale);
                }
            }
        }
    }
}

// ---------------------------------------------------------------------------
// Output projection WITH FUSED SPLIT-K MERGE (r20 bugfix: full 16B reg-stage):
// out = merge(Opart, Stat) @ Wo + bo. Per K-step (= head kt), each lane loads
// BOTH split-K fp16 partial 16B fragments + stats, merges 8 elems in regs
// (same math as the old merge_kernel), ds_write_b128 to the SAME LDS layout
// the gload16 scatter produced. B (Wo) stays gload16. 128x64 tiles, grid 512.
// ---------------------------------------------------------------------------
__global__ __launch_bounds__(256) void gemm_o_kernel(
    const unsigned short* __restrict__ Opart, const float2* __restrict__ Stat,
    const unsigned short* __restrict__ Wt, const float* __restrict__ bias,
    float* __restrict__ C)
{
    __shared__ unsigned short Als[2][128 * 64];
    __shared__ unsigned short Bls[2][64 * 64];

    const int tid = threadIdx.x;
    const int lane = tid & 63;
    const int wid = tid >> 6;
    const int l31 = lane & 31;
    const int hi = lane >> 5;
    const int by = blockIdx.x & 31;
    const int bx = blockIdx.x >> 5;         // 0..15
    const int row0 = by * 128;
    const int wr = wid >> 1, wc = wid & 1;

    const int rl = lane >> 3;
    const int sl = lane & 7;
    const int ssrc = (sl ^ rl) * 8;         // elem offset within the 64-col K-step

    const unsigned short* Bbase = Wt + (size_t)(bx * 64 + wid * 16 + rl) * kD + ssrc;

    f32x16 acc0{}, acc1{};

    auto stageB = [&](int kt, int buf) {
        gload16(Bbase + kt * 64,                   &Bls[buf][(wid * 16) * 64]);
        gload16(Bbase + (size_t)8 * kD + kt * 64,  &Bls[buf][(wid * 16 + 8) * 64]);
    };

    // A reg-stage part 1: issue loads for K-step kt (head = kt); 16B each side
    uint4 pa_[4], pb_[4];
    float2 sa_[4], sb_[4];
    auto loadA = [&](int kt) {
#pragma unroll
        for (int i = 0; i < 4; ++i) {
            const int grow = row0 + wid * 32 + i * 8 + rl;     // global q row
            const int b_ = grow >> 11, l_ = grow & (kL - 1);
            const int bhq = (b_ * kH + kt) * kL + l_;          // Stat/Opart row
            const unsigned short* pa = Opart + (size_t)bhq * kHD + ssrc;
            pa_[i] = *(const uint4*)pa;
            pb_[i] = *(const uint4*)(pa + (size_t)32 * kL * kHD);
            sa_[i] = Stat[bhq];
            sb_[i] = Stat[32 * kL + bhq];
        }
    };
    // A reg-stage part 2: merge 8 elems + ds_write_b128 (math == old merge_kernel)
    auto writeA = [&](int buf) {
#pragma unroll
        for (int i = 0; i < 4; ++i) {
            const float inv = 1.f / (sa_[i].y + sb_[i].y);
            const float wa = sa_[i].y * inv, wb = sb_[i].y * inv;
            _Float16 ha[8], hb[8];
            *(uint4*)ha = pa_[i];
            *(uint4*)hb = pb_[i];
            uint4 w;
            w.x = pk2(wa * (float)ha[0] + wb * (float)hb[0],
                      wa * (float)ha[1] + wb * (float)hb[1]);
            w.y = pk2(wa * (float)ha[2] + wb * (float)hb[2],
                      wa * (float)ha[3] + wb * (float)hb[3]);
            w.z = pk2(wa * (float)ha[4] + wb * (float)hb[4],
                      wa * (float)ha[5] + wb * (float)hb[5]);
            w.w = pk2(wa * (float)ha[6] + wb * (float)hb[6],
                      wa * (float)ha[7] + wb * (float)hb[7]);
            *(uint4*)&Als[buf][(wid * 32 + i * 8 + rl) * 64 + sl * 8] = w;
        }
    };

    const int ra0 = wr * 64 + l31;
    const int cb0 = wc * 32 + l31;

    // prologue: fill buffer 0
    loadA(0);
    stageB(0, 0);
    writeA(0);
    int cur = 0;
    for (int kt = 0; kt < kD / 64; ++kt) {
        __syncthreads();                    // buf[cur] complete for all waves
        if (kt + 1 < kD / 64) {
            loadA(kt + 1);                  // global loads overlap MFMA below
            stageB(kt + 1, cur ^ 1);
        }
#pragma unroll
        for (int ks = 0; ks < 4; ++ks) {
            const int slot = (ks << 1) | hi;
            Frag16 a0, a1, b0;
            a0.u4 = *(const uint4*)&Als[cur][ra0 * 64 + ((slot ^ (ra0 & 7)) << 3)];
            a1.u4 = *(const uint4*)&Als[cur][(ra0 + 32) * 64 + ((slot ^ ((ra0 + 32) & 7)) << 3)];
            b0.u4 = *(const uint4*)&Bls[cur][cb0 * 64 + ((slot ^ (cb0 & 7)) << 3)];
            acc0 = __builtin_amdgcn_mfma_f32_32x32x16_f16(a0.v, b0.v, acc0, 0, 0, 0);
            acc1 = __builtin_amdgcn_mfma_f32_32x32x16_f16(a1.v, b0.v, acc1, 0, 0, 0);
        }
        if (kt + 1 < kD / 64) writeA(cur ^ 1);   // merge lands after MFMA issues
        cur ^= 1;
    }

    const int c = (bx << 6) + wc * 32 + l31;
    const float bb = bias[c];
    const f32x16* accs[2] = {&acc0, &acc1};
#pragma unroll
    for (int rt = 0; rt < 2; ++rt) {
        const f32x16& acv = *accs[rt];
#pragma unroll
        for (int reg = 0; reg < 16; ++reg) {
            const int r = row0 + wr * 64 + rt * 32 + (reg & 3) + 8 * (reg >> 2) + 4 * hi;
            C[(size_t)r * kD + c] = acv[reg] + bb;
        }
    }
}

// ---------------------------------------------------------------------------
// MFMA flash attention, zero-shuffle P path + intra-round overlap (r19 best):
// QK(A+B) -> prefetch V(A) -> exp(A) -> PV(A) -> prefetch V(B) -> exp(B) ->
// PV(B). No max-tracking; Q pre-scaled; V key-quad-permuted. 8 waves,
// 4-buffer LDS, split-K x2, XCD-grouped.
// ---------------------------------------------------------------------------
__global__ __launch_bounds__(512) void attn_mfma_kernel(
    const unsigned short* __restrict__ Qh, const unsigned short* __restrict__ Kh,
    const unsigned short* __restrict__ Vt, unsigned short* __restrict__ Opart,
    float2* __restrict__ Stat)
{
    __shared__ unsigned short Kls[4][64 * 64];
    __shared__ unsigned short Vls[4][64 * 64];

    const int lane = threadIdx.x & 63;
    const int wid  = threadIdx.x >> 6;       // 0..7
    const int l31  = lane & 31;
    const int hi   = lane >> 5;

    const int id = blockIdx.x;               // 0..511
    const int j  = id >> 3;                  // 0..63
    const int bh = (id & 7) * 4 + (j >> 4);  // 4 heads per XCD
    const int qt = j & 7;                    // 0..7 (256-row q tiles)
    const int ks = (j >> 3) & 1;             // K half
    const int q = qt * 256 + wid * 32 + l31;

    const size_t qkBase = (size_t)bh * kL * kHD;
    const unsigned short* Qp = Qh + qkBase + (size_t)q * kHD + hi * 8;
    Frag16 qf[4];
#pragma unroll
    for (int d = 0; d < 4; ++d) qf[d].u4 = *(const uint4*)(Qp + d * 16);

    const int srow = wid * 8 + (lane >> 3);
    const int soff = (((lane & 7) ^ (srow & 7)) << 3);
    const unsigned short* Kg = Kh + qkBase + (size_t)srow * kHD + soff;
    const unsigned short* Vg = Vt + (size_t)bh * kHD * kL + (size_t)srow * kL + soff;

    auto stage = [&](int kt, int buf) {
        gload16(Kg + (size_t)(kt * 64) * kHD, &Kls[buf][(wid * 8) * 64]);
        gload16(Vg + kt * 64,                 &Vls[buf][(wid * 8) * 64]);
    };

    f32x16 o0{}, o1{};
    float lsum = 0.f;
    const int rA = l31, rB = l31 + 32;

    const int kt0 = ks * 16;
    stage(kt0 + 0, 0);
    stage(kt0 + 1, 1);

    for (int rt = 0; rt < 8; ++rt) {
        const int t0 = 2 * rt;
        asm volatile("s_waitcnt vmcnt(0)" ::: "memory");
        __builtin_amdgcn_s_barrier();
        if (t0 + 3 < 16) {
            stage(kt0 + t0 + 2, (t0 + 2) & 3);
            stage(kt0 + t0 + 3, (t0 + 3) & 3);
        }
        const int bA = t0 & 3, bB = (t0 + 1) & 3;

        // ---- QK^T both tiles (4 independent chains)
        f32x16 c0{}, c1{}, c2{}, c3{};
        __builtin_amdgcn_s_setprio(1);
#pragma unroll
        for (int d = 0; d < 4; ++d) {
            const int s = (d << 1) | hi;
            Frag16 ka0, ka1, kb0, kb1;
            ka0.u4 = *(const uint4*)&Kls[bA][rA * 64 + ((s ^ (rA & 7)) << 3)];
            ka1.u4 = *(const uint4*)&Kls[bA][rB * 64 + ((s ^ (rB & 7)) << 3)];
            kb0.u4 = *(const uint4*)&Kls[bB][rA * 64 + ((s ^ (rA & 7)) << 3)];
            kb1.u4 = *(const uint4*)&Kls[bB][rB * 64 + ((s ^ (rB & 7)) << 3)];
            c0 = __builtin_amdgcn_mfma_f32_32x32x16_f16(ka0.v, qf[d].v, c0, 0, 0, 0);
            c1 = __builtin_amdgcn_mfma_f32_32x32x16_f16(ka1.v, qf[d].v, c1, 0, 0, 0);
            c2 = __builtin_amdgcn_mfma_f32_32x32x16_f16(kb0.v, qf[d].v, c2, 0, 0, 0);
            c3 = __builtin_amdgcn_mfma_f32_32x32x16_f16(kb1.v, qf[d].v, c3, 0, 0, 0);
        }
        __builtin_amdgcn_s_setprio(0);

        // ---- prefetch tile-A V frags (LDS latency hides under exp(A))
        Frag16 vA0[4], vA1[4];
#pragma unroll
        for (int ksl = 0; ksl < 4; ++ksl) {
            const int s = (ksl << 1) | hi;
            vA0[ksl].u4 = *(const uint4*)&Vls[bA][rA * 64 + ((s ^ (rA & 7)) << 3)];
            vA1[ksl].u4 = *(const uint4*)&Vls[bA][rB * 64 + ((s ^ (rB & 7)) << 3)];
        }

        // ---- exp tile A -> pfA (packed straight; V key-permuted)
        float rs = 0.f;
        Frag16 pfA[4];
#pragma unroll
        for (int i = 0; i < 8; ++i) {
            const float e0 = __builtin_amdgcn_exp2f(c0[2 * i]);
            const float e1 = __builtin_amdgcn_exp2f(c0[2 * i + 1]);
            const float e2 = __builtin_amdgcn_exp2f(c1[2 * i]);
            const float e3 = __builtin_amdgcn_exp2f(c1[2 * i + 1]);
            pfA[i >> 2].u[i & 3]       = pk2(e0, e1);
            pfA[2 + (i >> 2)].u[i & 3] = pk2(e2, e3);
            rs += (e0 + e1) + (e2 + e3);
        }

        // ---- PV(A) from prefetched regs
        __builtin_amdgcn_s_setprio(1);
#pragma unroll
        for (int ksl = 0; ksl < 4; ++ksl) {
            o0 = __builtin_amdgcn_mfma_f32_32x32x16_f16(vA0[ksl].v, pfA[ksl].v, o0, 0, 0, 0);
            o1 = __builtin_amdgcn_mfma_f32_32x32x16_f16(vA1[ksl].v, pfA[ksl].v, o1, 0, 0, 0);
        }
        __builtin_amdgcn_s_setprio(0);

        // ---- prefetch tile-B V frags (overlap exp(B))
        Frag16 vB0[4], vB1[4];
#pragma unroll
        for (int ksl = 0; ksl < 4; ++ksl) {
            const int s = (ksl << 1) | hi;
            vB0[ksl].u4 = *(const uint4*)&Vls[bB][rA * 64 + ((s ^ (rA & 7)) << 3)];
            vB1[ksl].u4 = *(const uint4*)&Vls[bB][rB * 64 + ((s ^ (rB & 7)) << 3)];
        }

        // ---- exp tile B -> pfB
        Frag16 pfB[4];
#pragma unroll
        for (int i = 0; i < 8; ++i) {
            const float e4 = __builtin_amdgcn_exp2f(c2[2 * i]);
            const float e5 = __builtin_amdgcn_exp2f(c2[2 * i + 1]);
            const float e6 = __builtin_amdgcn_exp2f(c3[2 * i]);
            const float e7 = __builtin_amdgcn_exp2f(c3[2 * i + 1]);
            pfB[i >> 2].u[i & 3]       = pk2(e4, e5);
            pfB[2 + (i >> 2)].u[i & 3] = pk2(e6, e7);
            rs += (e4 + e5) + (e6 + e7);
        }
        rs += __shfl_xor(rs, 32);
        lsum += rs;

        // ---- PV(B)
        __builtin_amdgcn_s_setprio(1);
#pragma unroll
        for (int ksl = 0; ksl < 4; ++ksl) {
            o0 = __builtin_amdgcn_mfma_f32_32x32x16_f16(vB0[ksl].v, pfB[ksl].v, o0, 0, 0, 0);
            o1 = __builtin_amdgcn_mfma_f32_32x32x16_f16(vB1[ksl].v, pfB[ksl].v, o1, 0, 0, 0);
        }
        __builtin_amdgcn_s_setprio(0);
    }

    // ---- epilogue: normalized fp16 partial + stats (m fixed at 0)
    const size_t prow = (size_t)ks * (32 * kL) + (size_t)bh * kL + q;
    const float inv = 1.f / lsum;
    unsigned short* pp = Opart + prow * kHD;
#pragma unroll
    for (int g = 0; g < 4; ++g) {
        const int d = g * 8 + hi * 4;
        uint2 w0, w1;
        w0.x = pk2(o0[4 * g + 0] * inv, o0[4 * g + 1] * inv);
        w0.y = pk2(o0[4 * g + 2] * inv, o0[4 * g + 3] * inv);
        w1.x = pk2(o1[4 * g + 0] * inv, o1[4 * g + 1] * inv);
        w1.y = pk2(o1[4 * g + 2] * inv, o1[4 * g + 3] * inv);
        *(uint2*)(pp + d) = w0;
        *(uint2*)(pp + 32 + d) = w1;
    }
    if (hi == 0) Stat[prow] = make_float2(0.f, lsum);
}

// ---------------------------------------------------------------------------
extern "C" void kernel_launch(void* const* d_in, const int* in_sizes, int n_in,
                              void* d_out, int out_size, void* d_ws, size_t ws_size,
                              hipStream_t stream)
{
    const float* q  = (const float*)d_in[0];
    const float* k  = (const float*)d_in[1];
    const float* v  = (const float*)d_in[2];
    const float* Wq = (const float*)d_in[3];
    const float* bq = (const float*)d_in[4];
    const float* Wk = (const float*)d_in[5];
    const float* bk = (const float*)d_in[6];
    const float* Wv = (const float*)d_in[7];
    const float* bv = (const float*)d_in[8];
    const float* Wo = (const float*)d_in[9];
    const float* bo = (const float*)d_in[10];
    float* out = (float*)d_out;

    const size_t MD = (size_t)kM * kD;   // 4M elems
    const size_t DD = (size_t)kD * kD;   // 1M elems
    unsigned short* A16 = (unsigned short*)d_ws;   // q|k|v casts, 3*MD
    unsigned short* Wt16 = A16 + 3 * MD;   // [q|k|v|o] contiguous
    unsigned short* Qh16 = Wt16 + 4 * DD;
    unsigned short* Kh16 = Qh16 + MD;
    unsigned short* Vt16 = Kh16 + MD;
    unsigned short* Opart = A16 + MD;          // k,v-cast regions (dead after QKV-proj)
    float2*         Stat  = (float2*)Wt16;     // Wq-t region (dead after QKV-proj)

    const dim3 blk(256);

    hipLaunchKernelGGL(prep_kernel, dim3(7168), blk, 0, stream,
                       q, k, v, A16, Wq, Wk, Wv, Wo, Wt16);

    hipLaunchKernelGGL(gemm_qkv_kernel, dim3(32 * 24), blk, 0, stream,
                       A16, Wt16, bq, bk, bv, Qh16, Kh16, Vt16);

    hipLaunchKernelGGL(attn_mfma_kernel, dim3(512), dim3(512), 0, stream,
                       Qh16, Kh16, Vt16, Opart, Stat);

    hipLaunchKernelGGL(gemm_o_kernel, dim3(32 * 16), blk, 0, stream,
                       Opart, Stat, Wt16 + 3 * DD, bo, out);
}

// Round 22
// 118.612 us; speedup vs baseline: 1.0474x; 1.0474x over previous
//
#include <hip/hip_runtime.h>

namespace {
constexpr int kB  = 2;
constexpr int kL  = 2048;
constexpr int kD  = 1024;
constexpr int kH  = 16;
constexpr int kHD = 64;
constexpr int kM  = kB * kL;      // 4096 total rows
}

typedef _Float16 f16x8 __attribute__((ext_vector_type(8)));
typedef float    f32x16 __attribute__((ext_vector_type(16)));
typedef unsigned int u32;

union Frag16 { uint4 u4; unsigned u[4]; f16x8 v; };

__device__ __forceinline__ unsigned short f2h(float f) {
    return __builtin_bit_cast(unsigned short, (_Float16)f);
}
__device__ __forceinline__ unsigned pk2(float a, float b) {
    return __builtin_bit_cast(unsigned, __builtin_amdgcn_cvt_pkrtz(a, b));
}

// async 16B global -> LDS (wave-uniform LDS base; HW adds lane*16)
__device__ __forceinline__ void gload16(const void* g, void* l) {
    __builtin_amdgcn_global_load_lds(
        (const __attribute__((address_space(1))) u32*)g,
        (__attribute__((address_space(3))) u32*)(unsigned long long)(__builtin_bit_cast(unsigned long long, l)),
        16, 0, 0);
}

// ---------------------------------------------------------------------------
// Fused prep: blocks 0..6143 cast q,k,v fp32->fp16; blocks 6144..7167
// transpose-cast the 4 weight matrices to [n][k] fp16. One launch, grid 7168.
// ---------------------------------------------------------------------------
__global__ __launch_bounds__(256) void prep_kernel(
    const float* __restrict__ q, const float* __restrict__ k,
    const float* __restrict__ v, unsigned short* __restrict__ dstA,
    const float* __restrict__ W0, const float* __restrict__ W1,
    const float* __restrict__ W2, const float* __restrict__ W3,
    unsigned short* __restrict__ WtBase)
{
    __shared__ _Float16 T[64][68];
    const int id = blockIdx.x;
    if (id < 6144) {
        const int yy = id >> 11;            // 0..2 (src select)
        const int xx = id & 2047;
        const float* src = yy == 0 ? q : (yy == 1 ? k : v);
        unsigned short* d = dstA + (size_t)yy * ((size_t)kM * kD);
        const size_t i = ((size_t)xx * 256 + threadIdx.x) * 8;
        const float4 f0 = *(const float4*)(src + i);
        const float4 f1 = *(const float4*)(src + i + 4);
        _Float16 h[8];
        h[0] = (_Float16)f0.x; h[1] = (_Float16)f0.y;
        h[2] = (_Float16)f0.z; h[3] = (_Float16)f0.w;
        h[4] = (_Float16)f1.x; h[5] = (_Float16)f1.y;
        h[6] = (_Float16)f1.z; h[7] = (_Float16)f1.w;
        *(uint4*)(d + i) = *(uint4*)h;
        return;
    }
    const int id2 = id - 6144;              // 0..1023
    const int z = id2 >> 8;                 // weight select
    const int rem = id2 & 255;
    const int by = rem >> 4, bx = rem & 15;
    const float* W = z == 0 ? W0 : z == 1 ? W1 : z == 2 ? W2 : W3;
    unsigned short* Wt = WtBase + (size_t)z * ((size_t)kD * kD);
    const int k0 = by * 64, n0 = bx * 64;
    const int tx = threadIdx.x & 15, ty = threadIdx.x >> 4;
#pragma unroll
    for (int i = 0; i < 4; ++i) {
        const int kk = i * 16 + ty;
        const float4 w = *(const float4*)&W[(size_t)(k0 + kk) * kD + n0 + tx * 4];
        T[tx * 4 + 0][kk] = (_Float16)w.x;
        T[tx * 4 + 1][kk] = (_Float16)w.y;
        T[tx * 4 + 2][kk] = (_Float16)w.z;
        T[tx * 4 + 3][kk] = (_Float16)w.w;
    }
    __syncthreads();
#pragma unroll
    for (int i = 0; i < 4; ++i) {
        const int nn = i * 16 + ty;
        *(ushort4*)&Wt[(size_t)(n0 + nn) * kD + k0 + tx * 4] = *(ushort4*)&T[nn][tx * 4];
    }
}

// ---------------------------------------------------------------------------
// Fused QKV fp16 GEMM, 128x128/BK=64/2-buffer, grid 768 (2 blocks/CU).
// proj=bxp>>3; A at A+proj*MD, W at Wt+proj*DD.
// Q -> heads, PRE-SCALED by 0.125*log2(e). K -> heads. V -> transposed heads
// (B,H,HD,L) with keys QUAD-PERMUTED (l ^= 12 on middle quads) so attention's
// P-fragments need no cross-lane exchange.
// ---------------------------------------------------------------------------
__global__ __launch_bounds__(256) void gemm_qkv_kernel(
    const unsigned short* __restrict__ A, const unsigned short* __restrict__ Wt,
    const float* __restrict__ bq, const float* __restrict__ bk,
    const float* __restrict__ bv, unsigned short* __restrict__ Qh,
    unsigned short* __restrict__ Kh, unsigned short* __restrict__ Vt)
{
    __shared__ unsigned short Als[2][128 * 64];
    __shared__ unsigned short Bls[2][128 * 64];

    const int tid = threadIdx.x;
    const int lane = tid & 63;
    const int wid = tid >> 6;
    const int l31 = lane & 31;
    const int hi = lane >> 5;
    const int by = blockIdx.x & 31;
    const int bxp = blockIdx.x >> 5;        // 0..23
    const int proj = bxp >> 3;              // 0=q 1=k 2=v
    const int bx = bxp & 7;                 // col tile within proj
    const int row0 = by * 128;
    const int col0 = bx * 128;
    const int wr = wid >> 1, wc = wid & 1;

    const int rl = lane >> 3;
    const int sl = lane & 7;
    const int ssrc = (sl ^ rl) * 8;

    const unsigned short* Aproj = A + (size_t)proj * ((size_t)kM * kD);
    const unsigned short* Wproj = Wt + (size_t)proj * ((size_t)kD * kD);
    const unsigned short* Abase = Aproj + (size_t)(row0 + wid * 32 + rl) * kD + ssrc;
    const unsigned short* Bbase = Wproj + (size_t)(col0 + wid * 32 + rl) * kD + ssrc;

    f32x16 acc00{}, acc01{}, acc10{}, acc11{};

    auto stage = [&](int kt, int buf) {
#pragma unroll
        for (int i = 0; i < 4; ++i) {
            gload16(Abase + (size_t)(i * 8) * kD + kt * 64,
                    &Als[buf][(wid * 32 + i * 8) * 64]);
        }
#pragma unroll
        for (int i = 0; i < 4; ++i) {
            gload16(Bbase + (size_t)(i * 8) * kD + kt * 64,
                    &Bls[buf][(wid * 32 + i * 8) * 64]);
        }
    };

    const int ra0 = wr * 64 + l31;
    const int cb0 = wc * 64 + l31;

    stage(0, 0);
    int cur = 0;
    for (int kt = 0; kt < kD / 64; ++kt) {
        __syncthreads();
        if (kt + 1 < kD / 64) stage(kt + 1, cur ^ 1);
#pragma unroll
        for (int ks = 0; ks < 4; ++ks) {
            const int slot = (ks << 1) | hi;
            Frag16 a0, a1, b0, b1;
            a0.u4 = *(const uint4*)&Als[cur][ra0 * 64 + ((slot ^ (ra0 & 7)) << 3)];
            a1.u4 = *(const uint4*)&Als[cur][(ra0 + 32) * 64 + ((slot ^ ((ra0 + 32) & 7)) << 3)];
            b0.u4 = *(const uint4*)&Bls[cur][cb0 * 64 + ((slot ^ (cb0 & 7)) << 3)];
            b1.u4 = *(const uint4*)&Bls[cur][(cb0 + 32) * 64 + ((slot ^ ((cb0 + 32) & 7)) << 3)];
            acc00 = __builtin_amdgcn_mfma_f32_32x32x16_f16(a0.v, b0.v, acc00, 0, 0, 0);
            acc01 = __builtin_amdgcn_mfma_f32_32x32x16_f16(a0.v, b1.v, acc01, 0, 0, 0);
            acc10 = __builtin_amdgcn_mfma_f32_32x32x16_f16(a1.v, b0.v, acc10, 0, 0, 0);
            acc11 = __builtin_amdgcn_mfma_f32_32x32x16_f16(a1.v, b1.v, acc11, 0, 0, 0);
        }
        cur ^= 1;
    }

    // ---- epilogue ----
    const float* bias = proj == 0 ? bq : (proj == 1 ? bk : bv);
    const float bias0 = bias[col0 + wc * 64 + l31];
    const float bias1 = bias[col0 + wc * 64 + 32 + l31];
    const float oscale = proj == 0 ? (0.125f * 1.44269504089f) : 1.0f;

    const f32x16* accs[2][2] = {{&acc00, &acc01}, {&acc10, &acc11}};
#pragma unroll
    for (int rt = 0; rt < 2; ++rt) {
#pragma unroll
        for (int ct = 0; ct < 2; ++ct) {
            const f32x16& acv = *accs[rt][ct];
            const float bb = ct ? bias1 : bias0;
            const int c = col0 + wc * 64 + ct * 32 + l31;
            if (proj == 2) {
                // V transposed heads: [b][h][hd][l], l quad-permuted (1<->2 per 16)
#pragma unroll
                for (int qd = 0; qd < 4; ++qd) {
                    const int r = row0 + wr * 64 + rt * 32 + 8 * qd + 4 * hi;
                    const int b_ = r >> 11;
                    int l_ = r & (kL - 1);
                    l_ ^= ((((l_ >> 2) ^ (l_ >> 3)) & 1) ? 12 : 0);
                    ushort4 w;
                    w.x = f2h(acv[4 * qd + 0] + bb);
                    w.y = f2h(acv[4 * qd + 1] + bb);
                    w.z = f2h(acv[4 * qd + 2] + bb);
                    w.w = f2h(acv[4 * qd + 3] + bb);
                    *(ushort4*)&Vt[((size_t)(b_ * kH + (c >> 6)) * kHD + (c & 63)) * kL + l_] = w;
                }
            } else {
                unsigned short* C = proj == 0 ? Qh : Kh;
#pragma unroll
                for (int reg = 0; reg < 16; ++reg) {
                    const int r = row0 + wr * 64 + rt * 32 + (reg & 3) + 8 * (reg >> 2) + 4 * hi;
                    const int b_ = r >> 11, l_ = r & (kL - 1);
                    C[((size_t)(b_ * kH + (c >> 6)) * kL + l_) * kHD + (c & 63)] =
                        f2h((acv[reg] + bb) * oscale);
                }
            }
        }
    }
}

// ---------------------------------------------------------------------------
// Output projection (r19 proven): out = O16 @ Wo + bo. 128x64 tiles, grid 512.
// ---------------------------------------------------------------------------
__global__ __launch_bounds__(256) void gemm_o_kernel(
    const unsigned short* __restrict__ A, const unsigned short* __restrict__ Wt,
    const float* __restrict__ bias, float* __restrict__ C)
{
    __shared__ unsigned short Als[2][128 * 64];
    __shared__ unsigned short Bls[2][64 * 64];

    const int tid = threadIdx.x;
    const int lane = tid & 63;
    const int wid = tid >> 6;
    const int l31 = lane & 31;
    const int hi = lane >> 5;
    const int by = blockIdx.x & 31;
    const int bx = blockIdx.x >> 5;         // 0..15
    const int row0 = by * 128;
    const int wr = wid >> 1, wc = wid & 1;

    const int rl = lane >> 3;
    const int sl = lane & 7;
    const int ssrc = (sl ^ rl) * 8;

    const unsigned short* Abase = A + (size_t)(row0 + wid * 32 + rl) * kD + ssrc;
    const unsigned short* Bbase = Wt + (size_t)(bx * 64 + wid * 16 + rl) * kD + ssrc;

    f32x16 acc0{}, acc1{};

    auto stage = [&](int kt, int buf) {
#pragma unroll
        for (int i = 0; i < 4; ++i)
            gload16(Abase + (size_t)(i * 8) * kD + kt * 64,
                    &Als[buf][(wid * 32 + i * 8) * 64]);
        gload16(Bbase + kt * 64,                   &Bls[buf][(wid * 16) * 64]);
        gload16(Bbase + (size_t)8 * kD + kt * 64,  &Bls[buf][(wid * 16 + 8) * 64]);
    };

    const int ra0 = wr * 64 + l31;
    const int cb0 = wc * 32 + l31;

    stage(0, 0);
    int cur = 0;
    for (int kt = 0; kt < kD / 64; ++kt) {
        __syncthreads();
        if (kt + 1 < kD / 64) stage(kt + 1, cur ^ 1);
#pragma unroll
        for (int ks = 0; ks < 4; ++ks) {
            const int slot = (ks << 1) | hi;
            Frag16 a0, a1, b0;
            a0.u4 = *(const uint4*)&Als[cur][ra0 * 64 + ((slot ^ (ra0 & 7)) << 3)];
            a1.u4 = *(const uint4*)&Als[cur][(ra0 + 32) * 64 + ((slot ^ ((ra0 + 32) & 7)) << 3)];
            b0.u4 = *(const uint4*)&Bls[cur][cb0 * 64 + ((slot ^ (cb0 & 7)) << 3)];
            acc0 = __builtin_amdgcn_mfma_f32_32x32x16_f16(a0.v, b0.v, acc0, 0, 0, 0);
            acc1 = __builtin_amdgcn_mfma_f32_32x32x16_f16(a1.v, b0.v, acc1, 0, 0, 0);
        }
        cur ^= 1;
    }

    const int c = (bx << 6) + wc * 32 + l31;
    const float bb = bias[c];
    const f32x16* accs[2] = {&acc0, &acc1};
#pragma unroll
    for (int rt = 0; rt < 2; ++rt) {
        const f32x16& acv = *accs[rt];
#pragma unroll
        for (int reg = 0; reg < 16; ++reg) {
            const int r = row0 + wr * 64 + rt * 32 + (reg & 3) + 8 * (reg >> 2) + 4 * hi;
            C[(size_t)r * kD + c] = acv[reg] + bb;
        }
    }
}

// ---------------------------------------------------------------------------
// MFMA flash attention, zero-shuffle P path + intra-round overlap.
// lsum cross-lane reduce hoisted to the epilogue (linear in rounds).
// No max-tracking; Q pre-scaled; V key-quad-permuted. 8 waves, 4-buffer LDS,
// split-K x2, XCD-grouped.
// ---------------------------------------------------------------------------
__global__ __launch_bounds__(512) void attn_mfma_kernel(
    const unsigned short* __restrict__ Qh, const unsigned short* __restrict__ Kh,
    const unsigned short* __restrict__ Vt, unsigned short* __restrict__ Opart,
    float2* __restrict__ Stat)
{
    __shared__ unsigned short Kls[4][64 * 64];
    __shared__ unsigned short Vls[4][64 * 64];

    const int lane = threadIdx.x & 63;
    const int wid  = threadIdx.x >> 6;       // 0..7
    const int l31  = lane & 31;
    const int hi   = lane >> 5;

    const int id = blockIdx.x;               // 0..511
    const int j  = id >> 3;                  // 0..63
    const int bh = (id & 7) * 4 + (j >> 4);  // 4 heads per XCD
    const int qt = j & 7;                    // 0..7 (256-row q tiles)
    const int ks = (j >> 3) & 1;             // K half
    const int q = qt * 256 + wid * 32 + l31;

    const size_t qkBase = (size_t)bh * kL * kHD;
    const unsigned short* Qp = Qh + qkBase + (size_t)q * kHD + hi * 8;
    Frag16 qf[4];
#pragma unroll
    for (int d = 0; d < 4; ++d) qf[d].u4 = *(const uint4*)(Qp + d * 16);

    const int srow = wid * 8 + (lane >> 3);
    const int soff = (((lane & 7) ^ (srow & 7)) << 3);
    const unsigned short* Kg = Kh + qkBase + (size_t)srow * kHD + soff;
    const unsigned short* Vg = Vt + (size_t)bh * kHD * kL + (size_t)srow * kL + soff;

    auto stage = [&](int kt, int buf) {
        gload16(Kg + (size_t)(kt * 64) * kHD, &Kls[buf][(wid * 8) * 64]);
        gload16(Vg + kt * 64,                 &Vls[buf][(wid * 8) * 64]);
    };

    f32x16 o0{}, o1{};
    float lsum = 0.f;                        // per-lane partial; reduced once at end
    const int rA = l31, rB = l31 + 32;

    const int kt0 = ks * 16;
    stage(kt0 + 0, 0);
    stage(kt0 + 1, 1);

    for (int rt = 0; rt < 8; ++rt) {
        const int t0 = 2 * rt;
        asm volatile("s_waitcnt vmcnt(0)" ::: "memory");
        __builtin_amdgcn_s_barrier();
        if (t0 + 3 < 16) {
            stage(kt0 + t0 + 2, (t0 + 2) & 3);
            stage(kt0 + t0 + 3, (t0 + 3) & 3);
        }
        const int bA = t0 & 3, bB = (t0 + 1) & 3;

        // ---- QK^T both tiles (4 independent chains)
        f32x16 c0{}, c1{}, c2{}, c3{};
        __builtin_amdgcn_s_setprio(1);
#pragma unroll
        for (int d = 0; d < 4; ++d) {
            const int s = (d << 1) | hi;
            Frag16 ka0, ka1, kb0, kb1;
            ka0.u4 = *(const uint4*)&Kls[bA][rA * 64 + ((s ^ (rA & 7)) << 3)];
            ka1.u4 = *(const uint4*)&Kls[bA][rB * 64 + ((s ^ (rB & 7)) << 3)];
            kb0.u4 = *(const uint4*)&Kls[bB][rA * 64 + ((s ^ (rA & 7)) << 3)];
            kb1.u4 = *(const uint4*)&Kls[bB][rB * 64 + ((s ^ (rB & 7)) << 3)];
            c0 = __builtin_amdgcn_mfma_f32_32x32x16_f16(ka0.v, qf[d].v, c0, 0, 0, 0);
            c1 = __builtin_amdgcn_mfma_f32_32x32x16_f16(ka1.v, qf[d].v, c1, 0, 0, 0);
            c2 = __builtin_amdgcn_mfma_f32_32x32x16_f16(kb0.v, qf[d].v, c2, 0, 0, 0);
            c3 = __builtin_amdgcn_mfma_f32_32x32x16_f16(kb1.v, qf[d].v, c3, 0, 0, 0);
        }
        __builtin_amdgcn_s_setprio(0);

        // ---- prefetch tile-A V frags (LDS latency hides under exp(A))
        Frag16 vA0[4], vA1[4];
#pragma unroll
        for (int ksl = 0; ksl < 4; ++ksl) {
            const int s = (ksl << 1) | hi;
            vA0[ksl].u4 = *(const uint4*)&Vls[bA][rA * 64 + ((s ^ (rA & 7)) << 3)];
            vA1[ksl].u4 = *(const uint4*)&Vls[bA][rB * 64 + ((s ^ (rB & 7)) << 3)];
        }

        // ---- exp tile A -> pfA (packed straight; V key-permuted)
        Frag16 pfA[4];
#pragma unroll
        for (int i = 0; i < 8; ++i) {
            const float e0 = __builtin_amdgcn_exp2f(c0[2 * i]);
            const float e1 = __builtin_amdgcn_exp2f(c0[2 * i + 1]);
            const float e2 = __builtin_amdgcn_exp2f(c1[2 * i]);
            const float e3 = __builtin_amdgcn_exp2f(c1[2 * i + 1]);
            pfA[i >> 2].u[i & 3]       = pk2(e0, e1);
            pfA[2 + (i >> 2)].u[i & 3] = pk2(e2, e3);
            lsum += (e0 + e1) + (e2 + e3);
        }

        // ---- PV(A) from prefetched regs
        __builtin_amdgcn_s_setprio(1);
#pragma unroll
        for (int ksl = 0; ksl < 4; ++ksl) {
            o0 = __builtin_amdgcn_mfma_f32_32x32x16_f16(vA0[ksl].v, pfA[ksl].v, o0, 0, 0, 0);
            o1 = __builtin_amdgcn_mfma_f32_32x32x16_f16(vA1[ksl].v, pfA[ksl].v, o1, 0, 0, 0);
        }
        __builtin_amdgcn_s_setprio(0);

        // ---- prefetch tile-B V frags (overlap exp(B))
        Frag16 vB0[4], vB1[4];
#pragma unroll
        for (int ksl = 0; ksl < 4; ++ksl) {
            const int s = (ksl << 1) | hi;
            vB0[ksl].u4 = *(const uint4*)&Vls[bB][rA * 64 + ((s ^ (rA & 7)) << 3)];
            vB1[ksl].u4 = *(const uint4*)&Vls[bB][rB * 64 + ((s ^ (rB & 7)) << 3)];
        }

        // ---- exp tile B -> pfB
        Frag16 pfB[4];
#pragma unroll
        for (int i = 0; i < 8; ++i) {
            const float e4 = __builtin_amdgcn_exp2f(c2[2 * i]);
            const float e5 = __builtin_amdgcn_exp2f(c2[2 * i + 1]);
            const float e6 = __builtin_amdgcn_exp2f(c3[2 * i]);
            const float e7 = __builtin_amdgcn_exp2f(c3[2 * i + 1]);
            pfB[i >> 2].u[i & 3]       = pk2(e4, e5);
            pfB[2 + (i >> 2)].u[i & 3] = pk2(e6, e7);
            lsum += (e4 + e5) + (e6 + e7);
        }

        // ---- PV(B)
        __builtin_amdgcn_s_setprio(1);
#pragma unroll
        for (int ksl = 0; ksl < 4; ++ksl) {
            o0 = __builtin_amdgcn_mfma_f32_32x32x16_f16(vB0[ksl].v, pfB[ksl].v, o0, 0, 0, 0);
            o1 = __builtin_amdgcn_mfma_f32_32x32x16_f16(vB1[ksl].v, pfB[ksl].v, o1, 0, 0, 0);
        }
        __builtin_amdgcn_s_setprio(0);
    }

    // ---- epilogue: single cross-lane lsum reduce, normalize, store
    lsum += __shfl_xor(lsum, 32);
    const size_t prow = (size_t)ks * (32 * kL) + (size_t)bh * kL + q;
    const float inv = 1.f / lsum;
    unsigned short* pp = Opart + prow * kHD;
#pragma unroll
    for (int g = 0; g < 4; ++g) {
        const int d = g * 8 + hi * 4;
        uint2 w0, w1;
        w0.x = pk2(o0[4 * g + 0] * inv, o0[4 * g + 1] * inv);
        w0.y = pk2(o0[4 * g + 2] * inv, o0[4 * g + 3] * inv);
        w1.x = pk2(o1[4 * g + 0] * inv, o1[4 * g + 1] * inv);
        w1.y = pk2(o1[4 * g + 2] * inv, o1[4 * g + 3] * inv);
        *(uint2*)(pp + d) = w0;
        *(uint2*)(pp + 32 + d) = w1;
    }
    if (hi == 0) Stat[prow] = make_float2(0.f, lsum);
}

// ---------------------------------------------------------------------------
// Merge split-K partials -> fp16 O (B, L, D). grid 2048 x 256. (m == 0)
// ---------------------------------------------------------------------------
__global__ __launch_bounds__(256) void merge_kernel(
    const unsigned short* __restrict__ Opart, const float2* __restrict__ Stat,
    unsigned short* __restrict__ O16)
{
    const int g = blockIdx.x * 256 + threadIdx.x;   // 0 .. 2^19-1
    const int row = g >> 3;                         // bh*2048 + q
    const int d0 = (g & 7) * 8;
    const int bh = row >> 11, q = row & (kL - 1);
    const float2 sa = Stat[row];
    const float2 sb = Stat[32 * kL + row];
    float wa = sa.y;
    float wb = sb.y;
    const float inv = 1.f / (wa + wb);
    wa *= inv; wb *= inv;

    const unsigned short* pa = Opart + (size_t)row * kHD + d0;
    const unsigned short* pb = pa + (size_t)32 * kL * kHD;
    uint4 ua = *(const uint4*)pa;
    uint4 ub = *(const uint4*)pb;
    _Float16 ha[8], hb[8];
    *(uint4*)ha = ua;
    *(uint4*)hb = ub;
    unsigned out[4];
#pragma unroll
    for (int i = 0; i < 4; ++i) {
        const float v0 = wa * (float)ha[2 * i]     + wb * (float)hb[2 * i];
        const float v1 = wa * (float)ha[2 * i + 1] + wb * (float)hb[2 * i + 1];
        out[i] = pk2(v0, v1);
    }
    const int b_ = bh >> 4, h_ = bh & 15;
    *(uint4*)&O16[((size_t)(b_ * kL + q)) * kD + h_ * kHD + d0] = *(uint4*)out;
}

// ---------------------------------------------------------------------------
extern "C" void kernel_launch(void* const* d_in, const int* in_sizes, int n_in,
                              void* d_out, int out_size, void* d_ws, size_t ws_size,
                              hipStream_t stream)
{
    const float* q  = (const float*)d_in[0];
    const float* k  = (const float*)d_in[1];
    const float* v  = (const float*)d_in[2];
    const float* Wq = (const float*)d_in[3];
    const float* bq = (const float*)d_in[4];
    const float* Wk = (const float*)d_in[5];
    const float* bk = (const float*)d_in[6];
    const float* Wv = (const float*)d_in[7];
    const float* bv = (const float*)d_in[8];
    const float* Wo = (const float*)d_in[9];
    const float* bo = (const float*)d_in[10];
    float* out = (float*)d_out;

    const size_t MD = (size_t)kM * kD;   // 4M elems
    const size_t DD = (size_t)kD * kD;   // 1M elems
    unsigned short* A16 = (unsigned short*)d_ws;   // q|k|v casts, 3*MD
    unsigned short* Wt16 = A16 + 3 * MD;   // [q|k|v|o] contiguous
    unsigned short* Qh16 = Wt16 + 4 * DD;
    unsigned short* Kh16 = Qh16 + MD;
    unsigned short* Vt16 = Kh16 + MD;
    unsigned short* O16   = A16;               // q-cast region (dead after QKV-proj)
    unsigned short* Opart = A16 + MD;          // k,v-cast regions (dead after QKV-proj)
    float2*         Stat  = (float2*)Wt16;     // Wq-t region (dead after QKV-proj)

    const dim3 blk(256);

    hipLaunchKernelGGL(prep_kernel, dim3(7168), blk, 0, stream,
                       q, k, v, A16, Wq, Wk, Wv, Wo, Wt16);

    hipLaunchKernelGGL(gemm_qkv_kernel, dim3(32 * 24), blk, 0, stream,
                       A16, Wt16, bq, bk, bv, Qh16, Kh16, Vt16);

    hipLaunchKernelGGL(attn_mfma_kernel, dim3(512), dim3(512), 0, stream,
                       Qh16, Kh16, Vt16, Opart, Stat);
    hipLaunchKernelGGL(merge_kernel, dim3(2048), blk, 0, stream,
                       Opart, Stat, O16);

    hipLaunchKernelGGL(gemm_o_kernel, dim3(32 * 16), blk, 0, stream,
                       O16, Wt16 + 3 * DD, bo, out);
}